// Round 5
// baseline (18783.252 us; speedup 1.0000x reference)
//
#include <hip/hip_runtime.h>
#include <hip/hip_bf16.h>

#define HD   1024
#define GD   4096   // 4*H
#define TT   4096
#define NWG  256

// ---------------------------------------------------------------- gx GEMM
// gx[t][n] = sum_k emb[tokens[t]][k] * Wih[n][k] + bih[n] + bhh[n]
// (embedding gather fused into the A-tile load)
#define BM 128
#define BN 128
#define BK 16
#define LDP 132

__global__ __launch_bounds__(256, 2) void gemm_gx(
    const int* __restrict__ tokens,
    const float* __restrict__ emb,    // VOCAB x HD
    const float* __restrict__ Wih,    // GD x HD
    const float* __restrict__ bih,
    const float* __restrict__ bhh,
    float* __restrict__ gxout)        // TT x GD
{
    __shared__ float As[BK][LDP];
    __shared__ float Bs[BK][LDP];
    const int tid = threadIdx.x;
    const int m0 = blockIdx.x * BM;
    const int n0 = blockIdx.y * BN;
    const int tx = tid & 15;
    const int ty = tid >> 4;

    const int quad = tid & 3;
    const int r0   = tid >> 2;                 // rows r0 and r0+64
    const int tok0 = tokens[m0 + r0];
    const int tok1 = tokens[m0 + r0 + 64];

    float acc[8][8] = {};

    for (int kt = 0; kt < HD; kt += BK) {
        float4 av0 = *reinterpret_cast<const float4*>(
            &emb[(size_t)tok0 * HD + kt + quad * 4]);
        float4 bv0 = *reinterpret_cast<const float4*>(
            &Wih[(size_t)(n0 + r0) * HD + kt + quad * 4]);
        float4 av1 = *reinterpret_cast<const float4*>(
            &emb[(size_t)tok1 * HD + kt + quad * 4]);
        float4 bv1 = *reinterpret_cast<const float4*>(
            &Wih[(size_t)(n0 + r0 + 64) * HD + kt + quad * 4]);
        As[quad * 4 + 0][r0] = av0.x;
        As[quad * 4 + 1][r0] = av0.y;
        As[quad * 4 + 2][r0] = av0.z;
        As[quad * 4 + 3][r0] = av0.w;
        Bs[quad * 4 + 0][r0] = bv0.x;
        Bs[quad * 4 + 1][r0] = bv0.y;
        Bs[quad * 4 + 2][r0] = bv0.z;
        Bs[quad * 4 + 3][r0] = bv0.w;
        As[quad * 4 + 0][r0 + 64] = av1.x;
        As[quad * 4 + 1][r0 + 64] = av1.y;
        As[quad * 4 + 2][r0 + 64] = av1.z;
        As[quad * 4 + 3][r0 + 64] = av1.w;
        Bs[quad * 4 + 0][r0 + 64] = bv1.x;
        Bs[quad * 4 + 1][r0 + 64] = bv1.y;
        Bs[quad * 4 + 2][r0 + 64] = bv1.z;
        Bs[quad * 4 + 3][r0 + 64] = bv1.w;
        __syncthreads();
#pragma unroll
        for (int k = 0; k < BK; ++k) {
            float4 a0 = *reinterpret_cast<const float4*>(&As[k][ty * 8]);
            float4 a1 = *reinterpret_cast<const float4*>(&As[k][ty * 8 + 4]);
            float4 b0 = *reinterpret_cast<const float4*>(&Bs[k][tx * 8]);
            float4 b1 = *reinterpret_cast<const float4*>(&Bs[k][tx * 8 + 4]);
            float a[8] = {a0.x, a0.y, a0.z, a0.w, a1.x, a1.y, a1.z, a1.w};
            float b[8] = {b0.x, b0.y, b0.z, b0.w, b1.x, b1.y, b1.z, b1.w};
#pragma unroll
            for (int i = 0; i < 8; ++i)
#pragma unroll
                for (int j = 0; j < 8; ++j)
                    acc[i][j] += a[i] * b[j];
        }
        __syncthreads();
    }

    float bias[8];
#pragma unroll
    for (int j = 0; j < 8; ++j) {
        int n = n0 + tx * 8 + j;
        bias[j] = bih[n] + bhh[n];
    }
#pragma unroll
    for (int i = 0; i < 8; ++i) {
        size_t o = (size_t)(m0 + ty * 8 + i) * GD + n0 + tx * 8;
        float4 s0 = {acc[i][0] + bias[0], acc[i][1] + bias[1],
                     acc[i][2] + bias[2], acc[i][3] + bias[3]};
        float4 s1 = {acc[i][4] + bias[4], acc[i][5] + bias[5],
                     acc[i][6] + bias[6], acc[i][7] + bias[7]};
        *reinterpret_cast<float4*>(&gxout[o]) = s0;
        *reinterpret_cast<float4*>(&gxout[o + 4]) = s1;
    }
}

// ---------------------------------------------------------------- LSTM scan
// 256 WGs x 256 threads (4 waves). Wave w of WG b owns h element j = b*4+w,
// computing all four gates (lane = gate*16 + chunk). Weight columns per
// thread are {chunk*4 + 64q + e} -> conflict-free float4 LDS reads.
// Cross-WG h broadcast: DENSE tagged u64 mailboxes (8KB/parity), ping-pong
// by step parity. Each consumer thread polls its 4 contiguous entries with
// TWO global_load_dwordx4 (agent scope) -> 8KB/WG/round, ~2MB device-wide
// per round: far under IC bandwidth, so round period ~= one load latency.
__device__ __forceinline__ float sigmoid_(float x) {
    return 1.f / (1.f + __expf(-x));
}
__device__ __forceinline__ float tanh_(float x) {
    return __builtin_fmaf(2.f, 1.f / (1.f + __expf(-2.f * x)), -1.f);
}
__device__ __forceinline__ float bcast_(float v, int l) {
    return __uint_as_float(__builtin_amdgcn_readlane(__float_as_uint(v), l));
}
__device__ __forceinline__ void lds_barrier_() {
    asm volatile("s_waitcnt lgkmcnt(0)" ::: "memory");
    __builtin_amdgcn_s_barrier();
}

using u32x4 = __attribute__((ext_vector_type(4))) unsigned int;

__global__ __launch_bounds__(256, 1) void lstm_scan(
    const float* __restrict__ gx,                 // TT x GD (includes biases)
    const float* __restrict__ whh,                // GD x HD
    float* __restrict__ out,                      // TT*HD + HD + HD
    unsigned long long* __restrict__ hbuf)        // 2 x HD (dense)
{
    const int tid   = threadIdx.x;
    const int b     = blockIdx.x;
    const int lane  = tid & 63;
    const int wv    = tid >> 6;          // wave id == jj
    const int chunk = lane & 15;         // col chunk
    const int gate  = lane >> 4;         // 0..3 (i,f,g,o)
    const int j     = b * 4 + wv;        // owned h element
    const int R     = gate * HD + j;     // weight row for this lane

    // weights -> registers (interleaved column layout)
    float w[64];
    {
        const float* wrow = whh + (size_t)R * HD;
#pragma unroll
        for (int q = 0; q < 16; ++q) {
            float4 v = *reinterpret_cast<const float4*>(&wrow[chunk * 4 + q * 64]);
            w[q * 4 + 0] = v.x; w[q * 4 + 1] = v.y;
            w[q * 4 + 2] = v.z; w[q * 4 + 3] = v.w;
        }
    }

    __shared__ float h_lds[2][HD];
#pragma unroll
    for (int q = 0; q < 4; ++q) h_lds[0][tid * 4 + q] = 0.f;   // h(0) = 0
    lds_barrier_();

    float c_reg = 0.f;
    float gx_cur = gx[R];                // step 1 value

    // polled WG (rotated by own WG id to de-lockstep line access);
    // tp == b happens iff tid == 0, which skips polling (own values go
    // through LDS directly).
    const int tp = (tid + b) & 255;
    unsigned long long* const pb0 = hbuf + (size_t)tp * 4;
    unsigned long long* const pb1 = hbuf + HD + (size_t)tp * 4;

    for (int s = 1; s <= TT; ++s) {
        const int cb = (s - 1) & 1;      // buffer holding h(s-1)
        const int nb = s & 1;            // buffer for h(s)

        // prefetch next step's gx (consumed next iteration; floats across
        // the barrier since we never drain vmcnt at the barrier)
        float gx_nxt = 0.f;
        if (s < TT) gx_nxt = gx[(size_t)s * GD + R];

        // dot product over h(s-1): 4 independent FMA chains
        float A0 = (chunk == 0) ? gx_cur : 0.f;
        float A1 = 0.f, A2 = 0.f, A3 = 0.f;
        {
            const float* hb = h_lds[cb];
#pragma unroll
            for (int q = 0; q < 4; ++q) {
                float4 h0 = *reinterpret_cast<const float4*>(&hb[chunk * 4 + (4 * q + 0) * 64]);
                float4 h1 = *reinterpret_cast<const float4*>(&hb[chunk * 4 + (4 * q + 1) * 64]);
                float4 h2 = *reinterpret_cast<const float4*>(&hb[chunk * 4 + (4 * q + 2) * 64]);
                float4 h3 = *reinterpret_cast<const float4*>(&hb[chunk * 4 + (4 * q + 3) * 64]);
                A0 = __builtin_fmaf(w[(4 * q + 0) * 4 + 0], h0.x, A0);
                A0 = __builtin_fmaf(w[(4 * q + 0) * 4 + 1], h0.y, A0);
                A0 = __builtin_fmaf(w[(4 * q + 0) * 4 + 2], h0.z, A0);
                A0 = __builtin_fmaf(w[(4 * q + 0) * 4 + 3], h0.w, A0);
                A1 = __builtin_fmaf(w[(4 * q + 1) * 4 + 0], h1.x, A1);
                A1 = __builtin_fmaf(w[(4 * q + 1) * 4 + 1], h1.y, A1);
                A1 = __builtin_fmaf(w[(4 * q + 1) * 4 + 2], h1.z, A1);
                A1 = __builtin_fmaf(w[(4 * q + 1) * 4 + 3], h1.w, A1);
                A2 = __builtin_fmaf(w[(4 * q + 2) * 4 + 0], h2.x, A2);
                A2 = __builtin_fmaf(w[(4 * q + 2) * 4 + 1], h2.y, A2);
                A2 = __builtin_fmaf(w[(4 * q + 2) * 4 + 2], h2.z, A2);
                A2 = __builtin_fmaf(w[(4 * q + 2) * 4 + 3], h2.w, A2);
                A3 = __builtin_fmaf(w[(4 * q + 3) * 4 + 0], h3.x, A3);
                A3 = __builtin_fmaf(w[(4 * q + 3) * 4 + 1], h3.y, A3);
                A3 = __builtin_fmaf(w[(4 * q + 3) * 4 + 2], h3.z, A3);
                A3 = __builtin_fmaf(w[(4 * q + 3) * 4 + 3], h3.w, A3);
            }
        }
        float acc = (A0 + A1) + (A2 + A3);
        // reduce within each 16-lane gate group
        acc += __shfl_xor(acc, 1, 64);
        acc += __shfl_xor(acc, 2, 64);
        acc += __shfl_xor(acc, 4, 64);
        acc += __shfl_xor(acc, 8, 64);
        // broadcast the four gate sums to every lane (SGPR path)
        float si = bcast_(acc, 0);
        float sf = bcast_(acc, 16);
        float sg = bcast_(acc, 32);
        float so = bcast_(acc, 48);

        // gate math, wave-uniform (replicated in all 64 lanes)
        float ii = sigmoid_(si);
        float ff = sigmoid_(sf);
        float gg = tanh_(sg);
        float oo = sigmoid_(so);
        c_reg = __builtin_fmaf(ff, c_reg, ii * gg);
        float hh = oo * tanh_(c_reg);

        if (s < TT) {
            // publish first (critical path for all other WGs)
            if (lane == 0) {
                unsigned long long pkt =
                    ((unsigned long long)(unsigned)s << 32) | __float_as_uint(hh);
                __hip_atomic_store(&hbuf[(size_t)nb * HD + j], pkt,
                                   __ATOMIC_RELAXED, __HIP_MEMORY_SCOPE_AGENT);
            }
            gx_cur = gx_nxt;

            // gather h(s): thread t polls WG tp's 4 dense entries with two
            // 16B agent-scope loads (one 128B line), continuous for the
            // first 6 rounds, then s_sleep backoff as a safety valve.
            if (tid != 0) {
                const unsigned int us = (unsigned int)s;
                unsigned long long* src = nb ? pb1 : pb0;
                u32x4 q0, q1;
                int r = 0;
                for (;;) {
                    asm volatile(
                        "global_load_dwordx4 %0, %2, off sc1\n\t"
                        "global_load_dwordx4 %1, %2, off offset:16 sc1\n\t"
                        "s_waitcnt vmcnt(0)"
                        : "=v"(q0), "=v"(q1)
                        : "v"(src)
                        : "memory");
                    bool ok = (q0.y == us) & (q0.w == us) &
                              (q1.y == us) & (q1.w == us);
                    if (ok) break;
                    ++r;
                    if (r > (1 << 17)) break;          // safety: never expected
                    if (r >= 6) __builtin_amdgcn_s_sleep(1);
                }
                float4 hv;
                hv.x = __uint_as_float(q0.x);
                hv.y = __uint_as_float(q0.z);
                hv.z = __uint_as_float(q1.x);
                hv.w = __uint_as_float(q1.z);
                *reinterpret_cast<float4*>(&h_lds[nb][tp * 4]) = hv;
            }
            if (lane == 0) {
                h_lds[nb][j] = hh;                     // own value, LDS path
                out[(size_t)(s - 1) * HD + j] = hh;    // hs output (floats)
            }
            lds_barrier_();
        } else {
            if (lane == 0) {
                out[(size_t)(s - 1) * HD + j] = hh;
                out[(size_t)TT * HD + j] = hh;          // h_n
                out[(size_t)TT * HD + HD + j] = c_reg;  // c_n
            }
        }
    }
}

// ---------------------------------------------------------------- launch
extern "C" void kernel_launch(void* const* d_in, const int* in_sizes, int n_in,
                              void* d_out, int out_size, void* d_ws, size_t ws_size,
                              hipStream_t stream) {
    const int*   tokens = (const int*)d_in[0];
    const float* emb    = (const float*)d_in[1];
    const float* w_ih   = (const float*)d_in[2];
    const float* w_hh   = (const float*)d_in[3];
    const float* b_ih   = (const float*)d_in[4];
    const float* b_hh   = (const float*)d_in[5];
    float* out = (float*)d_out;

    char* ws = (char*)d_ws;
    const size_t HBUF_BYTES = (size_t)2 * HD * 8;          // 16 KB dense
    unsigned long long* hbuf = (unsigned long long*)ws;
    float* gx = (float*)(ws + 65536);                      // 64 MB

    hipMemsetAsync(hbuf, 0, HBUF_BYTES, stream);
    gemm_gx<<<dim3(TT / BM, GD / BN), 256, 0, stream>>>(tokens, emb, w_ih,
                                                        b_ih, b_hh, gx);
    lstm_scan<<<NWG, 256, 0, stream>>>(gx, w_hh, out, hbuf);
}